// Round 8
// baseline (202.212 us; speedup 1.0000x reference)
//
#include <hip/hip_runtime.h>
#include <math.h>

#define SEQ 1024
#define DIM 1024
#define NH 16
#define HD 64
#define NB 2

typedef __attribute__((ext_vector_type(8))) short bf16x8;
typedef __attribute__((ext_vector_type(4))) float f32x4;
typedef __attribute__((ext_vector_type(8))) unsigned short ushort8;
typedef __attribute__((ext_vector_type(4))) unsigned short ushort4v;

#define DT_CONST (-0.2971077539347156f)   // -ln(10000)/31

__device__ __forceinline__ unsigned short f2bf(float x) {
    unsigned u = __float_as_uint(x);
    return (unsigned short)((u + 0x7fffu + ((u >> 16) & 1u)) >> 16);
}
__device__ __forceinline__ float bf2f(unsigned short h) {
    return __uint_as_float(((unsigned)h) << 16);
}
__device__ __forceinline__ void bfsplit(float x, unsigned short& hi, unsigned short& lo) {
    hi = f2bf(x);
    lo = f2bf(x - bf2f(hi));
}

// ---------------------------------------------------------------------------
// Fused conversion + trig-table kernel. grid (1024, 7):
//  y=0 query->split  y=1 key->split  y=2 value->plain (2M elems)
//  y=3 Wq->split     y=4 Wv->plain   y=5 Wo->plain    (1M elems)
//  y=6 trig table Kt[j,c] (64K elems)
// ---------------------------------------------------------------------------
__device__ __forceinline__ void split8(const float* __restrict__ s,
                                       unsigned short* __restrict__ h,
                                       unsigned short* __restrict__ l, int i) {
    float4 v0 = *(const float4*)&s[i];
    float4 v1 = *(const float4*)&s[i + 4];
    float vs[8] = {v0.x, v0.y, v0.z, v0.w, v1.x, v1.y, v1.z, v1.w};
    ushort8 hv, lv;
    #pragma unroll
    for (int k = 0; k < 8; ++k) {
        unsigned short hi, lo;
        bfsplit(vs[k], hi, lo);
        hv[k] = hi; lv[k] = lo;
    }
    *(ushort8*)&h[i] = hv;
    *(ushort8*)&l[i] = lv;
}
__device__ __forceinline__ void plain8(const float* __restrict__ s,
                                       unsigned short* __restrict__ h, int i) {
    float4 v0 = *(const float4*)&s[i];
    float4 v1 = *(const float4*)&s[i + 4];
    float vs[8] = {v0.x, v0.y, v0.z, v0.w, v1.x, v1.y, v1.z, v1.w};
    ushort8 hv;
    #pragma unroll
    for (int k = 0; k < 8; ++k) hv[k] = f2bf(vs[k]);
    *(ushort8*)&h[i] = hv;
}

__global__ __launch_bounds__(256) void conv_all(
    const float* __restrict__ query, const float* __restrict__ key,
    const float* __restrict__ value, const float* __restrict__ Wq,
    const float* __restrict__ Wv, const float* __restrict__ Wo,
    unsigned short* __restrict__ Aqh, unsigned short* __restrict__ Aql,
    unsigned short* __restrict__ Khs, unsigned short* __restrict__ Kls,
    unsigned short* __restrict__ Vb,
    unsigned short* __restrict__ Wqh, unsigned short* __restrict__ Wql,
    unsigned short* __restrict__ Wvh, unsigned short* __restrict__ Woh,
    unsigned short* __restrict__ Kth, unsigned short* __restrict__ Ktl)
{
    int i = (blockIdx.x * 256 + threadIdx.x) * 8;
    int r = blockIdx.y;
    const int NSMALL = DIM * DIM;
    if (r >= 3 && r <= 5 && i >= NSMALL) return;
    if (r == 6 && i >= SEQ * HD) return;
    switch (r) {
        case 0: split8(query, Aqh, Aql, i); break;
        case 1: split8(key,   Khs, Kls, i); break;
        case 2: plain8(value, Vb, i); break;
        case 3: split8(Wq, Wqh, Wql, i); break;
        case 4: plain8(Wv, Wvh, i); break;
        case 5: plain8(Wo, Woh, i); break;
        case 6: {
            #pragma unroll
            for (int k = 0; k < 8; ++k) {
                int idx = i + k;
                int j = idx >> 6;
                int c = idx & 63;
                int ii = c & 31;
                float dt = __expf((float)ii * DT_CONST);
                float ang = (float)j * dt;
                float val = (c < 32) ? sinf(ang) : cosf(ang);
                unsigned short hi, lo;
                bfsplit(val, hi, lo);
                Kth[idx] = hi;
                Ktl[idx] = lo;
            }
            break;
        }
    }
}

// ---------------------------------------------------------------------------
// Fused q-proj + v-proj GEMM, 64x64 tiles, 4 waves (wave w: rows w*16..+15,
// all 64 cols). grid (16 heads, 32 m-tiles, 2). z=0: q split-bf16 (3 MFMA),
// fused Q'' epilogue. z=1: v plain, transposed+permuted epilogue into vpT.
// ---------------------------------------------------------------------------
__global__ __launch_bounds__(256) void qv_gemm(
    const unsigned short* __restrict__ Aqh, const unsigned short* __restrict__ Aql,
    const unsigned short* __restrict__ Wqh, const unsigned short* __restrict__ Wql,
    const float* __restrict__ bq,
    const unsigned short* __restrict__ Vb, const unsigned short* __restrict__ Wvh,
    const float* __restrict__ bv,
    const float* __restrict__ v_bias,
    unsigned short* __restrict__ Qh, unsigned short* __restrict__ Ql,
    unsigned short* __restrict__ vpT)
{
    __shared__ __align__(16) unsigned short smem[8192];   // 16 KB
    unsigned short (*sAh)[32] = (unsigned short(*)[32])smem;          // 64x32
    unsigned short (*sAl)[32] = (unsigned short(*)[32])(smem + 2048);
    unsigned short (*sWh)[32] = (unsigned short(*)[32])(smem + 4096);
    unsigned short (*sWl)[32] = (unsigned short(*)[32])(smem + 6144);

    const int K = DIM;
    bool isq = (blockIdx.z == 0);

    int tid = threadIdx.x;
    int lane = tid & 63;
    int w = tid >> 6;
    int l16 = lane & 15, quad = lane >> 4;
    int m0 = blockIdx.y * 64;
    int h = blockIdx.x;
    int n0 = h * 64;

    int ar = tid >> 2, ap = (tid & 3) << 3;   // 64 rows x 4 ushort8 each

    const unsigned short* pAh = (isq ? Aqh : Vb) + (size_t)(m0 + ar) * K + ap;
    const unsigned short* pWh = (isq ? Wqh : Wvh) + (size_t)(n0 + ar) * K + ap;
    const unsigned short* pAl = Aql + (size_t)(m0 + ar) * K + ap;
    const unsigned short* pWl = Wql + (size_t)(n0 + ar) * K + ap;

    f32x4 acc[4];
    #pragma unroll
    for (int nt = 0; nt < 4; ++nt) acc[nt] = (f32x4){0.f, 0.f, 0.f, 0.f};

    ushort8 ra, rb, la, lb;
    ra = *(const ushort8*)pAh;
    rb = *(const ushort8*)pWh;
    if (isq) { la = *(const ushort8*)pAl; lb = *(const ushort8*)pWl; }

    for (int kk = 0; kk < K; kk += 32) {
        __syncthreads();
        *(ushort8*)&sAh[ar][ap] = ra;
        *(ushort8*)&sWh[ar][ap] = rb;
        if (isq) {
            *(ushort8*)&sAl[ar][ap] = la;
            *(ushort8*)&sWl[ar][ap] = lb;
        }
        if (kk + 32 < K) {
            ra = *(const ushort8*)(pAh + kk + 32);
            rb = *(const ushort8*)(pWh + kk + 32);
            if (isq) {
                la = *(const ushort8*)(pAl + kk + 32);
                lb = *(const ushort8*)(pWl + kk + 32);
            }
        }
        __syncthreads();

        bf16x8 af, bf[4], afl, bfl[4];
        af = *(const bf16x8*)&sAh[w * 16 + l16][quad * 8];
        if (isq) afl = *(const bf16x8*)&sAl[w * 16 + l16][quad * 8];
        #pragma unroll
        for (int nt = 0; nt < 4; ++nt) {
            bf[nt] = *(const bf16x8*)&sWh[nt * 16 + l16][quad * 8];
            if (isq) bfl[nt] = *(const bf16x8*)&sWl[nt * 16 + l16][quad * 8];
        }
        #pragma unroll
        for (int nt = 0; nt < 4; ++nt) {
            acc[nt] = __builtin_amdgcn_mfma_f32_16x16x32_bf16(af, bf[nt], acc[nt], 0, 0, 0);
            if (isq) {
                acc[nt] = __builtin_amdgcn_mfma_f32_16x16x32_bf16(afl, bf[nt], acc[nt], 0, 0, 0);
                acc[nt] = __builtin_amdgcn_mfma_f32_16x16x32_bf16(af, bfl[nt], acc[nt], 0, 0, 0);
            }
        }
    }

    int b = m0 >> 10;

    if (isq) {
        // ---- fused Q'' epilogue: head vals + trig-combined coefs, hi/lo ----
        float bql[4], vbs[2], vbc[2], dti[2];
        #pragma unroll
        for (int nt = 0; nt < 4; ++nt) bql[nt] = bq[h * 64 + nt * 16 + l16];
        #pragma unroll
        for (int t = 0; t < 2; ++t) {
            vbs[t] = v_bias[h * 64 + t * 16 + l16];
            vbc[t] = v_bias[h * 64 + 32 + t * 16 + l16];
            dti[t] = __expf((float)(t * 16 + l16) * DT_CONST);
        }
        #pragma unroll
        for (int reg = 0; reg < 4; ++reg) {
            int row = m0 + w * 16 + quad * 4 + reg;
            int q = row & (SEQ - 1);
            size_t qbase = ((size_t)(b * NH + h) * SEQ + q) * 128;
            float hv[4];
            #pragma unroll
            for (int nt = 0; nt < 4; ++nt) hv[nt] = acc[nt][reg] + bql[nt];
            #pragma unroll
            for (int nt = 0; nt < 4; ++nt) {
                unsigned short hi, lo;
                bfsplit(hv[nt], hi, lo);
                Qh[qbase + nt * 16 + l16] = hi;
                Ql[qbase + nt * 16 + l16] = lo;
            }
            #pragma unroll
            for (int t = 0; t < 2; ++t) {
                float u = hv[t] + vbs[t];
                float wv = hv[t + 2] + vbc[t];
                float ang = (float)q * dti[t];
                float C = cosf(ang), S = sinf(ang);
                float cs = u * C + wv * S;
                float cc = wv * C - u * S;
                unsigned short hi, lo;
                bfsplit(cs, hi, lo);
                Qh[qbase + 64 + t * 16 + l16] = hi;
                Ql[qbase + 64 + t * 16 + l16] = lo;
                bfsplit(cc, hi, lo);
                Qh[qbase + 96 + t * 16 + l16] = hi;
                Ql[qbase + 96 + t * 16 + l16] = lo;
            }
        }
    } else {
        // ---- transposed + k-permuted epilogue into vpT[b,h,dd,s] ----
        __syncthreads();
        unsigned short* tb = smem;   // [64][72]
        #pragma unroll
        for (int nt = 0; nt < 4; ++nt) {
            int d = nt * 16 + l16;
            float bcol = bv[n0 + d];
            #pragma unroll
            for (int reg = 0; reg < 4; ++reg) {
                int srow = w * 16 + quad * 4 + reg;
                tb[d * 72 + srow] = f2bf(acc[nt][reg] + bcol);
            }
        }
        __syncthreads();
        int s0 = m0 & (SEQ - 1);
        #pragma unroll
        for (int i = tid; i < 512; i += 256) {
            int dd = i >> 3;
            int posl = (i & 7) << 3;
            unsigned short tmp[8];
            #pragma unroll
            for (int k = 0; k < 8; ++k) {
                int pos = posl + k;
                int sl = (pos >> 2) + (pos & 3) * 16;   // inverse permutation
                tmp[k] = tb[dd * 72 + sl];
            }
            *(ushort8*)&vpT[((size_t)((b * NH + h) * 64 + dd)) * SEQ + s0 + posl] =
                *(ushort8*)tmp;
        }
    }
}

// ---------------------------------------------------------------------------
// Output GEMM: 64x64 tiles, 512 blocks. out = xab(bf16) @ Woh^T + bo, f32.
// ---------------------------------------------------------------------------
__global__ __launch_bounds__(256) void out_gemm(
    const unsigned short* __restrict__ Ab, const unsigned short* __restrict__ Woh,
    const float* __restrict__ bo, float* __restrict__ C)
{
    __shared__ unsigned short sA[64][32];
    __shared__ unsigned short sW[64][32];

    const int K = DIM, N = DIM;
    int tid = threadIdx.x;
    int lane = tid & 63;
    int w = tid >> 6;
    int l16 = lane & 15, quad = lane >> 4;
    int m0 = blockIdx.y * 64, n0 = blockIdx.x * 64;

    int ar = tid >> 2, ap = (tid & 3) << 3;

    const unsigned short* pA = Ab + (size_t)(m0 + ar) * K + ap;
    const unsigned short* pW = Woh + (size_t)(n0 + ar) * K + ap;

    f32x4 acc[4];
    #pragma unroll
    for (int nt = 0; nt < 4; ++nt) acc[nt] = (f32x4){0.f, 0.f, 0.f, 0.f};

    ushort8 a0 = *(const ushort8*)pA;
    ushort8 w0 = *(const ushort8*)pW;

    for (int kk = 0; kk < K; kk += 32) {
        __syncthreads();
        *(ushort8*)&sA[ar][ap] = a0;
        *(ushort8*)&sW[ar][ap] = w0;
        if (kk + 32 < K) {
            a0 = *(const ushort8*)(pA + kk + 32);
            w0 = *(const ushort8*)(pW + kk + 32);
        }
        __syncthreads();

        bf16x8 af = *(const bf16x8*)&sA[w * 16 + l16][quad * 8];
        bf16x8 bf[4];
        #pragma unroll
        for (int nt = 0; nt < 4; ++nt)
            bf[nt] = *(const bf16x8*)&sW[nt * 16 + l16][quad * 8];
        #pragma unroll
        for (int nt = 0; nt < 4; ++nt)
            acc[nt] = __builtin_amdgcn_mfma_f32_16x16x32_bf16(af, bf[nt], acc[nt], 0, 0, 0);
    }

    #pragma unroll
    for (int nt = 0; nt < 4; ++nt) {
        int col = n0 + nt * 16 + l16;
        float bcol = bo[col];
        #pragma unroll
        for (int reg = 0; reg < 4; ++reg) {
            int row = m0 + w * 16 + quad * 4 + reg;
            C[(size_t)row * N + col] = acc[nt][reg] + bcol;
        }
    }
}

// ---------------------------------------------------------------------------
// Flash attention, 2-way j-split. Block = 256 thr (4 waves), 64 q-rows,
// one (b,h,split). Each split covers 8 j-tiles; emits un-normalized O (bf16)
// + (m,l) f32 per row. grid = 1024.
// ---------------------------------------------------------------------------
#define LDK 136
#define LDV 72

__global__ __launch_bounds__(256) void attn_mfma(
    const unsigned short* __restrict__ Kh,
    const unsigned short* __restrict__ Kl,
    const unsigned short* __restrict__ vpT,  // [B,H,64,S] (s permuted per 64-blk)
    const unsigned short* __restrict__ Qh,   // [B,H,S,128]
    const unsigned short* __restrict__ Ql,
    const unsigned short* __restrict__ Kth,  // [S,64]
    const unsigned short* __restrict__ Ktl,
    unsigned short* __restrict__ Opart,      // [2][B*NH*SEQ, 64] bf16
    float* __restrict__ ml)                  // [2][B*NH*SEQ, 2] f32
{
    __shared__ unsigned short Ksh[64][LDK];
    __shared__ unsigned short Ksl[64][LDK];
    __shared__ unsigned short Vt[64][LDV];
    __shared__ unsigned short Ps[64][LDV];

    int tid = threadIdx.x;
    int w = tid >> 6;
    int lane = tid & 63;
    int l16 = lane & 15;
    int quad = lane >> 4;

    int bid = blockIdx.x;
    int qt = bid & 15;
    int h = (bid >> 4) & 15;
    int b = (bid >> 8) & 1;
    int sp = bid >> 9;
    int q0 = qt << 6;
    int jb = sp << 3;            // first j-tile of this split

    int sr0 = tid >> 3, sp0 = (tid & 7) << 3;
    int sr1 = sr0 + 32;

    // ---- prefetch first j-tile ----
    ushort8 pKh0, pKl0, pTh0, pTl0, pV0, pKh1, pKl1, pTh1, pTl1, pV1;
    {
        int j0 = jb << 6;
        size_t g0 = (size_t)(b * SEQ + j0 + sr0) * DIM + h * HD + sp0;
        size_t g1 = (size_t)(b * SEQ + j0 + sr1) * DIM + h * HD + sp0;
        pKh0 = *(const ushort8*)&Kh[g0]; pKl0 = *(const ushort8*)&Kl[g0];
        pKh1 = *(const ushort8*)&Kh[g1]; pKl1 = *(const ushort8*)&Kl[g1];
        size_t t0 = (size_t)(j0 + sr0) * 64 + sp0, t1 = (size_t)(j0 + sr1) * 64 + sp0;
        pTh0 = *(const ushort8*)&Kth[t0]; pTl0 = *(const ushort8*)&Ktl[t0];
        pTh1 = *(const ushort8*)&Kth[t1]; pTl1 = *(const ushort8*)&Ktl[t1];
        size_t v0 = ((size_t)((b * NH + h) * 64 + sr0)) * SEQ + j0 + sp0;
        size_t v1 = ((size_t)((b * NH + h) * 64 + sr1)) * SEQ + j0 + sp0;
        pV0 = *(const ushort8*)&vpT[v0]; pV1 = *(const ushort8*)&vpT[v1];
    }

    // ---- stage Q'' into Ksh/Ksl, pull A-fragments ----
    {
        const unsigned short* gq = Qh + (((size_t)(b * NH + h)) * SEQ + q0) * 128;
        const unsigned short* gl = Ql + (((size_t)(b * NH + h)) * SEQ + q0) * 128;
        #pragma unroll
        for (int c = tid; c < 1024; c += 256) {
            int r = c >> 4, p = (c & 15) << 3;
            *(ushort8*)&Ksh[r][p] = *(const ushort8*)&gq[r * 128 + p];
            *(ushort8*)&Ksl[r][p] = *(const ushort8*)&gl[r * 128 + p];
        }
    }
    __syncthreads();

    bf16x8 ah[4], al[4];
    #pragma unroll
    for (int c = 0; c < 4; ++c) {
        ah[c] = *(const bf16x8*)&Ksh[w * 16 + l16][c * 32 + quad * 8];
        al[c] = *(const bf16x8*)&Ksl[w * 16 + l16][c * 32 + quad * 8];
    }

    f32x4 oacc[4];
    #pragma unroll
    for (int nb = 0; nb < 4; ++nb) oacc[nb] = (f32x4){0.f, 0.f, 0.f, 0.f};
    float mval[4] = {-INFINITY, -INFINITY, -INFINITY, -INFINITY};
    float lval[4] = {0.f, 0.f, 0.f, 0.f};

    for (int jt = 0; jt < 8; ++jt) {
        __syncthreads();
        *(ushort8*)&Ksh[sr0][sp0] = pKh0;  *(ushort8*)&Ksl[sr0][sp0] = pKl0;
        *(ushort8*)&Ksh[sr1][sp0] = pKh1;  *(ushort8*)&Ksl[sr1][sp0] = pKl1;
        *(ushort8*)&Ksh[sr0][64 + sp0] = pTh0; *(ushort8*)&Ksl[sr0][64 + sp0] = pTl0;
        *(ushort8*)&Ksh[sr1][64 + sp0] = pTh1; *(ushort8*)&Ksl[sr1][64 + sp0] = pTl1;
        *(ushort8*)&Vt[sr0][sp0] = pV0;    *(ushort8*)&Vt[sr1][sp0] = pV1;
        if (jt < 7) {
            int j0n = (jb + jt + 1) << 6;
            size_t g0 = (size_t)(b * SEQ + j0n + sr0) * DIM + h * HD + sp0;
            size_t g1 = (size_t)(b * SEQ + j0n + sr1) * DIM + h * HD + sp0;
            pKh0 = *(const ushort8*)&Kh[g0]; pKl0 = *(const ushort8*)&Kl[g0];
            pKh1 = *(const ushort8*)&Kh[g1]; pKl1 = *(const ushort8*)&Kl[g1];
            size_t t0 = (size_t)(j0n + sr0) * 64 + sp0, t1 = (size_t)(j0n + sr1) * 64 + sp0;
            pTh0 = *(const ushort8*)&Kth[t0]; pTl0 = *(const ushort8*)&Ktl[t0];
            pTh1 = *(const ushort8*)&Kth[t1]; pTl1 = *(const ushort8*)&Ktl[t1];
            size_t v0 = ((size_t)((b * NH + h) * 64 + sr0)) * SEQ + j0n + sp0;
            size_t v1 = ((size_t)((b * NH + h) * 64 + sr1)) * SEQ + j0n + sp0;
            pV0 = *(const ushort8*)&vpT[v0]; pV1 = *(const ushort8*)&vpT[v1];
        }
        __syncthreads();

        // ---- QK^T: S[16 x 64] per wave, split-bf16 ----
        f32x4 sacc[4];
        #pragma unroll
        for (int nb = 0; nb < 4; ++nb) {
            sacc[nb] = (f32x4){0.f, 0.f, 0.f, 0.f};
            #pragma unroll
            for (int c = 0; c < 4; ++c) {
                bf16x8 bh = *(const bf16x8*)&Ksh[nb * 16 + l16][c * 32 + quad * 8];
                bf16x8 bl = *(const bf16x8*)&Ksl[nb * 16 + l16][c * 32 + quad * 8];
                sacc[nb] = __builtin_amdgcn_mfma_f32_16x16x32_bf16(ah[c], bh, sacc[nb], 0, 0, 0);
                sacc[nb] = __builtin_amdgcn_mfma_f32_16x16x32_bf16(al[c], bh, sacc[nb], 0, 0, 0);
                sacc[nb] = __builtin_amdgcn_mfma_f32_16x16x32_bf16(ah[c], bl, sacc[nb], 0, 0, 0);
            }
        }

        // ---- online softmax; P stored k-permuted: pos = l16*4 + c ----
        #pragma unroll
        for (int r = 0; r < 4; ++r) {
            float v = fmaxf(fmaxf(sacc[0][r], sacc[1][r]), fmaxf(sacc[2][r], sacc[3][r]));
            #pragma unroll
            for (int mask = 1; mask < 16; mask <<= 1)
                v = fmaxf(v, __shfl_xor(v, mask, 64));
            float mnew = fmaxf(mval[r], v);
            float alpha = __expf(mval[r] - mnew);
            float p0 = __expf(sacc[0][r] - mnew);
            float p1 = __expf(sacc[1][r] - mnew);
            float p2 = __expf(sacc[2][r] - mnew);
            float p3 = __expf(sacc[3][r] - mnew);
            float rs = (p0 + p1) + (p2 + p3);
            #pragma unroll
            for (int mask = 1; mask < 16; mask <<= 1)
                rs += __shfl_xor(rs, mask, 64);
            lval[r] = lval[r] * alpha + rs;
            mval[r] = mnew;
            int prow = w * 16 + quad * 4 + r;
            ushort4v pv4;
            pv4.x = f2bf(p0); pv4.y = f2bf(p1); pv4.z = f2bf(p2); pv4.w = f2bf(p3);
            *(ushort4v*)&Ps[prow][l16 * 4] = pv4;
            oacc[0][r] *= alpha;
            oacc[1][r] *= alpha;
            oacc[2][r] *= alpha;
            oacc[3][r] *= alpha;
        }

        // ---- PV: O[16 x 64] += P * V (k-space permuted consistently) ----
        #pragma unroll
        for (int nb = 0; nb < 4; ++nb) {
            #pragma unroll
            for (int kc = 0; kc < 2; ++kc) {
                bf16x8 a = *(const bf16x8*)&Ps[w * 16 + l16][kc * 32 + quad * 8];
                bf16x8 bv = *(const bf16x8*)&Vt[nb * 16 + l16][kc * 32 + quad * 8];
                oacc[nb] = __builtin_amdgcn_mfma_f32_16x16x32_bf16(a, bv, oacc[nb], 0, 0, 0);
            }
        }
    }

    // ---- epilogue: un-normalized O + (m,l) ----
    const size_t OOFF = (size_t)sp * NB * NH * SEQ * 64;
    const size_t MLOFF = (size_t)sp * NB * NH * SEQ * 2;
    #pragma unroll
    for (int r = 0; r < 4; ++r) {
        int qrow = q0 + w * 16 + quad * 4 + r;
        size_t rowi = (size_t)(b * NH + h) * SEQ + qrow;
        #pragma unroll
        for (int nb = 0; nb < 4; ++nb)
            Opart[OOFF + rowi * 64 + nb * 16 + l16] = f2bf(oacc[nb][r]);
        if (l16 == 0) {
            ml[MLOFF + rowi * 2]     = mval[r];
            ml[MLOFF + rowi * 2 + 1] = lval[r];
        }
    }
}

// ---------------------------------------------------------------------------
// Combine the two j-splits: xab = (w0*O0 + w1*O1) / (w0*l0 + w1*l1), bf16.
// grid = B*NH*SEQ/4, block 256 (4 rows x 64 lanes).
// ---------------------------------------------------------------------------
__global__ __launch_bounds__(256) void attn_combine(
    const unsigned short* __restrict__ Opart, const float* __restrict__ ml,
    unsigned short* __restrict__ xab)
{
    const size_t OOFF = (size_t)NB * NH * SEQ * 64;
    const size_t MLOFF = (size_t)NB * NH * SEQ * 2;
    int tid = threadIdx.x;
    int d = tid & 63;
    size_t r = (size_t)blockIdx.x * 4 + (tid >> 6);
    int q = (int)(r & (SEQ - 1));
    int h = (int)((r >> 10) & (NH - 1));
    int b = (int)(r >> 14);

    float m0 = ml[r * 2], l0 = ml[r * 2 + 1];
    float m1 = ml[MLOFF + r * 2], l1 = ml[MLOFF + r * 2 + 1];
    float mx = fmaxf(m0, m1);
    float w0 = __expf(m0 - mx), w1 = __expf(m1 - mx);
    float inv = 1.f / (w0 * l0 + w1 * l1);
    float O0 = bf2f(Opart[r * 64 + d]);
    float O1 = bf2f(Opart[OOFF + r * 64 + d]);
    float o = (w0 * O0 + w1 * O1) * inv;
    xab[((size_t)(b * SEQ + q)) * DIM + h * HD + d] = f2bf(o);
}

// ---------------------------------------------------------------------------
extern "C" void kernel_launch(void* const* d_in, const int* in_sizes, int n_in,
                              void* d_out, int out_size, void* d_ws, size_t ws_size,
                              hipStream_t stream) {
    const float* query  = (const float*)d_in[0];
    const float* key    = (const float*)d_in[1];
    const float* value  = (const float*)d_in[2];
    // d_in[3]: mask — unused (reference softmax is unmasked)
    const float* Wq     = (const float*)d_in[4];
    const float* bq     = (const float*)d_in[5];
    const float* Wv     = (const float*)d_in[6];
    const float* bv     = (const float*)d_in[7];
    const float* Wo     = (const float*)d_in[8];
    const float* bo     = (const float*)d_in[9];
    const float* v_bias = (const float*)d_in[10];

    float* out = (float*)d_out;
    char* base = (char*)d_ws;
    const size_t MB = 1024 * 1024;

    // Aliasing plan (producer -> consumer ordering makes these safe):
    //  0- 4: Aqh (conv -> qv)            ; xab (combine -> out_gemm)
    //  4- 8: Aql (conv -> qv)            ; ml  (attn -> combine)
    //  8-12: vpT (qv -> attn)
    // 12-16: Khs, 16-20: Kls (conv -> attn)
    // 20-28: Qh, 28-36: Ql (qv -> attn)
    // 36-44: Wqh/Wql/Vb (conv -> qv)     ; Opart (attn -> combine)
    // 44-46: Wvh (conv -> qv)
    // 46-48: Woh (conv -> out_gemm)
    // 48+  : trig tables
    unsigned short* Aqh = (unsigned short*)base;
    unsigned short* xab = (unsigned short*)base;
    unsigned short* Aql = (unsigned short*)(base + 4 * MB);
    float*          ml  = (float*)(base + 4 * MB);
    unsigned short* vpT = (unsigned short*)(base + 8 * MB);
    unsigned short* Khs = (unsigned short*)(base + 12 * MB);
    unsigned short* Kls = (unsigned short*)(base + 16 * MB);
    unsigned short* Qh  = (unsigned short*)(base + 20 * MB);
    unsigned short* Ql  = (unsigned short*)(base + 28 * MB);
    unsigned short* Wqh = (unsigned short*)(base + 36 * MB);
    unsigned short* Wql = (unsigned short*)(base + 38 * MB);
    unsigned short* Opart = (unsigned short*)(base + 36 * MB);
    unsigned short* Vb  = (unsigned short*)(base + 40 * MB);
    unsigned short* Wvh = (unsigned short*)(base + 44 * MB);
    unsigned short* Woh = (unsigned short*)(base + 46 * MB);
    unsigned short* Kth = (unsigned short*)(base + 48 * MB);
    unsigned short* Ktl = Kth + (size_t)SEQ * 64;

    const int M = NB * SEQ;

    dim3 cgrid(M * DIM / 2048, 7);
    conv_all<<<cgrid, 256, 0, stream>>>(query, key, value, Wq, Wv, Wo,
                                        Aqh, Aql, Khs, Kls, Vb, Wqh, Wql, Wvh, Woh,
                                        Kth, Ktl);

    dim3 qvgrid(NH, M / 64, 2);
    qv_gemm<<<qvgrid, 256, 0, stream>>>(Aqh, Aql, Wqh, Wql, bq, Vb, Wvh, bv,
                                        v_bias, Qh, Ql, vpT);

    attn_mfma<<<2 * NB * NH * (SEQ / 64), 256, 0, stream>>>(Khs, Kls, vpT, Qh, Ql,
                                                            Kth, Ktl, Opart, ml);

    attn_combine<<<NB * NH * SEQ / 4, 256, 0, stream>>>(Opart, ml, xab);

    dim3 ogrid(DIM / 64, M / 64);
    out_gemm<<<ogrid, 256, 0, stream>>>(xab, Woh, bo, out);
}